// Round 4
// baseline (479.712 us; speedup 1.0000x reference)
//
#include <hip/hip_runtime.h>
#include <stdint.h>

#define M_DIM 8192
#define K_DIM 4096
#define N_DIM 4096
#define KTILES (K_DIM / 64)

typedef __attribute__((ext_vector_type(4))) int i32x4;
typedef __attribute__((ext_vector_type(16))) int i32x16;

// ---------------------------------------------------------------------------
// Pack int32-stored int8 weights [N,K] -> true int8 [N,K]; per-row sum folded
// into integer correction corr[n] = (128 - zp) * rowsum[n].
// ---------------------------------------------------------------------------
__global__ void pack_w_kernel(const int* __restrict__ w, char* __restrict__ wp,
                              int* __restrict__ corr, const int* __restrict__ zpp) {
  __shared__ int red[256];
  const int n = blockIdx.x;
  const int t = threadIdx.x;
  const int4* row = (const int4*)(w + (size_t)n * K_DIM);
  int s = 0;
  int words[4];
#pragma unroll
  for (int u = 0; u < 4; ++u) {
    int4 v = row[t * 4 + u];
    s += v.x + v.y + v.z + v.w;
    words[u] = (v.x & 255) | ((v.y & 255) << 8) | ((v.z & 255) << 16) | (v.w << 24);
  }
  ((int4*)(wp + (size_t)n * K_DIM))[t] = make_int4(words[0], words[1], words[2], words[3]);
  red[t] = s;
  __syncthreads();
  for (int off = 128; off > 0; off >>= 1) {
    if (t < off) red[t] += red[t + off];
    __syncthreads();
  }
  if (t == 0) corr[n] = (128 - zpp[0]) * red[0];
}

// ---------------------------------------------------------------------------
// Quantize fp32 input -> int8 (q - 128), 4 elements/thread.
// ---------------------------------------------------------------------------
__global__ void quant_in_kernel(const float* __restrict__ x, char* __restrict__ q,
                                const float* __restrict__ sp, const int* __restrict__ zpp) {
  const int i = blockIdx.x * blockDim.x + threadIdx.x;
  const float s = sp[0];
  const float zp = (float)zpp[0];
  float4 v = ((const float4*)x)[i];
  float t0 = fminf(fmaxf(rintf(v.x / s) + zp, 0.f), 255.f);
  float t1 = fminf(fmaxf(rintf(v.y / s) + zp, 0.f), 255.f);
  float t2 = fminf(fmaxf(rintf(v.z / s) + zp, 0.f), 255.f);
  float t3 = fminf(fmaxf(rintf(v.w / s) + zp, 0.f), 255.f);
  int b0 = (int)t0 - 128, b1 = (int)t1 - 128, b2 = (int)t2 - 128, b3 = (int)t3 - 128;
  ((int*)q)[i] = (b0 & 255) | ((b1 & 255) << 8) | ((b2 & 255) << 16) | (b3 << 24);
}

// ---------------------------------------------------------------------------
// 256x256 i8 GEMM, mfma_i32_32x32x32_i8, pipelined regs, 1 barrier/K-tile.
// 512 threads = 8 waves (2M x 4N), per-wave 128x64 out = 4mt x 2nt tiles of
// 32x32, 2 k-steps per BK=64 tile -> 16 MFMA/wave/tile, acc = 4x2 x i32x16.
// LDS: 4-slot ring (A 16KB + B 16KB per slot) = 128 KB, prefetch distance 3.
// Invariant at tile-t start: slots t, t+1 confirmed (vmcnt(4) per tile end
// confirms t+2), t+2 in flight. Per tile:
//   [read a1/b1(slot t)] [stage A(t+3)] SB(0) [MFMA ks=0]
//   [read next a0/b0(slot t+1)] [stage B(t+3)] SB(0) [MFMA ks=1]
//   vmcnt(4) barrier
// sched_barrier(0) pins read-issue BEFORE each MFMA cluster so the LDS pipe
// works under the matrix bursts (R3 alternated: 2540 cyc/tile = LDS+MFMA
// serial). Swizzle (0 conflicts R1-R3): slot_phys = slot ^ ((row>>1)&3),
// applied to global source at staging and to ds_read addr.
// ---------------------------------------------------------------------------
#define STAGE16(SRC, DST)                                                     \
  __builtin_amdgcn_global_load_lds(                                           \
      (const __attribute__((address_space(1))) void*)(SRC),                   \
      (__attribute__((address_space(3))) void*)(DST), 16, 0, 0)

#define RD(p) (*(const i32x4*)(p))

#define TILE(SLOT, KSTG, DO_NEXT)                                             \
  {                                                                           \
    const char* bufA_ = &lds[SLOT][0][0];                                     \
    const char* bufB_ = &lds[SLOT][1][0];                                     \
    char* nA_ = &lds[((SLOT) + 3) & 3][0][0];                                 \
    char* nB_ = &lds[((SLOT) + 3) & 3][1][0];                                 \
    i32x4 a1_[4], b1_[2];                                                     \
    _Pragma("unroll") for (int i_ = 0; i_ < 4; ++i_)                          \
        a1_[i_] = RD(bufA_ + aoff[4 + i_]);                                   \
    _Pragma("unroll") for (int j_ = 0; j_ < 2; ++j_)                          \
        b1_[j_] = RD(bufB_ + boff[2 + j_]);                                   \
    STAGE16(asrc0 + (size_t)(KSTG) * 64, nA_ + o0_);                          \
    STAGE16(asrc1 + (size_t)(KSTG) * 64, nA_ + o1_);                          \
    __builtin_amdgcn_sched_barrier(0);                                        \
    __builtin_amdgcn_s_setprio(1);                                            \
    _Pragma("unroll") for (int i_ = 0; i_ < 4; ++i_)                          \
        _Pragma("unroll") for (int j_ = 0; j_ < 2; ++j_)                      \
            acc[i_][j_] = __builtin_amdgcn_mfma_i32_32x32x32_i8(              \
                a0[i_], b0[j_], acc[i_][j_], 0, 0, 0);                        \
    __builtin_amdgcn_s_setprio(0);                                            \
    if (DO_NEXT) {                                                            \
      const char* xA_ = &lds[((SLOT) + 1) & 3][0][0];                         \
      const char* xB_ = &lds[((SLOT) + 1) & 3][1][0];                         \
      _Pragma("unroll") for (int i_ = 0; i_ < 4; ++i_)                        \
          a0[i_] = RD(xA_ + aoff[i_]);                                        \
      _Pragma("unroll") for (int j_ = 0; j_ < 2; ++j_)                        \
          b0[j_] = RD(xB_ + boff[j_]);                                        \
    }                                                                         \
    STAGE16(bsrc0 + (size_t)(KSTG) * 64, nB_ + o0_);                          \
    STAGE16(bsrc1 + (size_t)(KSTG) * 64, nB_ + o1_);                          \
    __builtin_amdgcn_sched_barrier(0);                                        \
    __builtin_amdgcn_s_setprio(1);                                            \
    _Pragma("unroll") for (int i_ = 0; i_ < 4; ++i_)                          \
        _Pragma("unroll") for (int j_ = 0; j_ < 2; ++j_)                      \
            acc[i_][j_] = __builtin_amdgcn_mfma_i32_32x32x32_i8(              \
                a1_[i_], b1_[j_], acc[i_][j_], 0, 0, 0);                      \
    __builtin_amdgcn_s_setprio(0);                                            \
    asm volatile("s_waitcnt vmcnt(4)" ::: "memory");                          \
    __builtin_amdgcn_s_barrier();                                             \
  }

template <int WRITE_Q>
__global__ __launch_bounds__(512, 2) void gemm_kernel(
    const char* __restrict__ qa, const char* __restrict__ wb,
    const int* __restrict__ corr, const float* __restrict__ swp,
    const float* __restrict__ bias, const float* __restrict__ sp,
    const int* __restrict__ zpp, char* __restrict__ outq, float* __restrict__ outf) {
  __shared__ __align__(16) char lds[4][2][16384];  // 128 KB: 4-slot ring
  const int tid = threadIdx.x;
  const int lane = tid & 63;
  const int w = tid >> 6;
  const int wr = w >> 2;   // 0..1 (M)
  const int wc = w & 3;    // 0..3 (N)
  const int bid = blockIdx.x;
  const int bm = bid & 31;  // M/256 = 32, fastest: neighbors share B panel
  const int bn = bid >> 5;  // N/256 = 16
  const char* abase = qa + (size_t)bm * 256 * K_DIM;
  const char* bbase = wb + (size_t)bn * 256 * K_DIM;

  // --- per-thread staging constants (inverse-swizzled global sources) ---
  const int o0_ = tid * 16;
  const int o1_ = 8192 + tid * 16;
  const int r0_ = o0_ >> 6, r1_ = o1_ >> 6;
  const int g0_ = ((o0_ >> 4) & 3) ^ ((r0_ >> 1) & 3);
  const int g1_ = ((o1_ >> 4) & 3) ^ ((r1_ >> 1) & 3);
  const char* asrc0 = abase + (size_t)r0_ * K_DIM + g0_ * 16;
  const char* asrc1 = abase + (size_t)r1_ * K_DIM + g1_ * 16;
  const char* bsrc0 = bbase + (size_t)r0_ * K_DIM + g0_ * 16;
  const char* bsrc1 = bbase + (size_t)r1_ * K_DIM + g1_ * 16;

  // --- per-thread ds_read byte offsets (swizzled), 32x32 fragment layout ---
  // A/B frag: lane holds 16 bytes of row (base + lane&31) at k-byte
  // (ks*32 + (lane>>5)*16). slot = ks*2 + (lane>>5); phys = slot^((row>>1)&3).
  const int r32 = lane & 31;
  const int kh = lane >> 5;
  int aoff[8], boff[4];
#pragma unroll
  for (int ks = 0; ks < 2; ++ks) {
#pragma unroll
    for (int mt = 0; mt < 4; ++mt) {
      const int row = wr * 128 + mt * 32 + r32;
      const int slot = ks * 2 + kh;
      aoff[ks * 4 + mt] = (row << 6) + ((slot ^ ((row >> 1) & 3)) << 4);
    }
#pragma unroll
    for (int nt = 0; nt < 2; ++nt) {
      const int row = wc * 64 + nt * 32 + r32;
      const int slot = ks * 2 + kh;
      boff[ks * 2 + nt] = (row << 6) + ((slot ^ ((row >> 1) & 3)) << 4);
    }
  }

  i32x16 acc[4][2] = {};

  // --- prologue: stage slots 0,1,2 (tiles 0,1,2); confirm slots 0 AND 1 ---
  STAGE16(asrc0, &lds[0][0][o0_]); STAGE16(asrc1, &lds[0][0][o1_]);
  STAGE16(bsrc0, &lds[0][1][o0_]); STAGE16(bsrc1, &lds[0][1][o1_]);
  STAGE16(asrc0 + 64, &lds[1][0][o0_]); STAGE16(asrc1 + 64, &lds[1][0][o1_]);
  STAGE16(bsrc0 + 64, &lds[1][1][o0_]); STAGE16(bsrc1 + 64, &lds[1][1][o1_]);
  STAGE16(asrc0 + 128, &lds[2][0][o0_]); STAGE16(asrc1 + 128, &lds[2][0][o1_]);
  STAGE16(bsrc0 + 128, &lds[2][1][o0_]); STAGE16(bsrc1 + 128, &lds[2][1][o1_]);
  asm volatile("s_waitcnt vmcnt(4)" ::: "memory");  // slots 0,1 confirmed
  __builtin_amdgcn_s_barrier();

  i32x4 a0[4], b0[2];
#pragma unroll
  for (int i = 0; i < 4; ++i) a0[i] = RD(&lds[0][0][0] + aoff[i]);
#pragma unroll
  for (int j = 0; j < 2; ++j) b0[j] = RD(&lds[0][1][0] + boff[j]);

  // --- main loop: t = 0..59 (slots cycle 0..3) ---
  for (int tb = 0; tb < (KTILES - 4) / 4; ++tb) {
    const int t0 = tb * 4;
#pragma unroll
    for (int u = 0; u < 4; ++u) {
      TILE(u, t0 + u + 3, 1);
    }
  }
  // --- peeled tail: t = 60..63; stage kt clamps to 63 (re-stage) ---
  TILE(0, KTILES - 1, 1);
  TILE(1, KTILES - 1, 1);
  TILE(2, KTILES - 1, 1);
  TILE(3, KTILES - 1, 0);
  asm volatile("s_waitcnt vmcnt(0)" ::: "memory");  // drain before exit

  // --- epilogue: 32x32 C/D: n = lane&31, m = (r&3) + 8*(r>>2) + 4*(lane>>5)
  const float s = sp[0];
  const float zpf = (float)zpp[0];
  const int lm = kh * 4;
#pragma unroll
  for (int nt = 0; nt < 2; ++nt) {
    const int n = bn * 256 + wc * 64 + nt * 32 + r32;
    const int cr = corr[n];
    const float fs = s * swp[n];
    const float bb = bias[n];
#pragma unroll
    for (int mt = 0; mt < 4; ++mt) {
      const int mb = bm * 256 + wr * 128 + mt * 32 + lm;
#pragma unroll
      for (int r = 0; r < 16; ++r) {
        const int m = mb + (r & 3) + 8 * (r >> 2);
        float val = fs * (float)(acc[mt][nt][r] + cr) + bb;
        if (WRITE_Q) {
          float tq = fminf(fmaxf(rintf(val / s) + zpf, 0.f), 255.f);
          outq[(size_t)m * N_DIM + n] = (char)((int)tq - 128);
        } else {
          outf[(size_t)m * N_DIM + n] = val;
        }
      }
    }
  }
}

// ---------------------------------------------------------------------------
extern "C" void kernel_launch(void* const* d_in, const int* in_sizes, int n_in,
                              void* d_out, int out_size, void* d_ws, size_t ws_size,
                              hipStream_t stream) {
  const float* x = (const float*)d_in[0];
  const int* wq = (const int*)d_in[1];
  const float* bias = (const float*)d_in[2];
  const float* s_in = (const float*)d_in[3];
  const int* zp_in = (const int*)d_in[4];
  const float* s_w = (const float*)d_in[5];
  float* out = (float*)d_out;

  const size_t WP_BYTES = (size_t)N_DIM * K_DIM;  // 16 MB packed int8 W
  const size_t Q_BYTES = (size_t)M_DIM * K_DIM;   // 32 MB int8 activations
  char* ws = (char*)d_ws;
  char* wp = ws;
  char* q1 = ws + WP_BYTES;
  char* q2 = q1 + Q_BYTES;
  int* corr = (int*)(q2 + Q_BYTES);
  const size_t NEEDED = WP_BYTES + 2 * Q_BYTES + (size_t)N_DIM * sizeof(int);
  if (ws_size < NEEDED) return;

  pack_w_kernel<<<N_DIM, 256, 0, stream>>>(wq, wp, corr, zp_in);
  quant_in_kernel<<<(M_DIM * K_DIM / 4) / 256, 256, 0, stream>>>(x, q1, s_in, zp_in);

  dim3 grid((M_DIM / 256) * (N_DIM / 256));  // 512 blocks
  dim3 blk(512);
  gemm_kernel<1><<<grid, blk, 0, stream>>>(q1, wp, corr, s_w, bias, s_in, zp_in, q2, nullptr);
  gemm_kernel<1><<<grid, blk, 0, stream>>>(q2, wp, corr, s_w, bias, s_in, zp_in, q1, nullptr);
  gemm_kernel<0><<<grid, blk, 0, stream>>>(q1, wp, corr, s_w, bias, s_in, zp_in, nullptr, out);
}